// Round 1
// baseline (1379.133 us; speedup 1.0000x reference)
//
#include <hip/hip_runtime.h>
#include <cstdint>
#include <cstddef>

typedef unsigned short u16;
typedef short bf16x8 __attribute__((ext_vector_type(8)));
typedef float f32x4 __attribute__((ext_vector_type(4)));
typedef u16 u16x4 __attribute__((ext_vector_type(4)));

#define NTOK 8192
#define HID 1024
#define NEXP 8
#define FF 4096
#define FCHUNK 1024
#define NCHUNK 4
#define MAXPAIR 17408   // 2*NTOK + NEXP*128 padding headroom
#define BM 128
#define BN 128
#define BK 64

__device__ __forceinline__ u16 bf16_rne(float f) {
  unsigned u = __builtin_bit_cast(unsigned, f);
  return (u16)((u + 0x7FFFu + ((u >> 16) & 1u)) >> 16);
}

__device__ __forceinline__ void async16(const void* g, void* l) {
  __builtin_amdgcn_global_load_lds(
      (const __attribute__((address_space(1))) void*)g,
      (__attribute__((address_space(3))) void*)l, 16, 0, 0);
}

// ---------------- gate: logits, top-2, softmax probs ----------------
__global__ __launch_bounds__(256) void gate_kernel(
    const float* __restrict__ x, const float* __restrict__ gw,
    const float* __restrict__ gb, int* __restrict__ counts,
    float* __restrict__ probs_sum, int* __restrict__ topk_e,
    float* __restrict__ topk_w) {
  __shared__ float sgw[NEXP * HID];
  __shared__ float sProbs[NEXP];
  __shared__ int sCnt[NEXP];
  const int tid = threadIdx.x;
  for (int i = tid; i < NEXP * HID; i += 256) sgw[i] = gw[i];
  if (tid < NEXP) { sProbs[tid] = 0.f; sCnt[tid] = 0; }
  __syncthreads();
  const int lane = tid & 63, wave = tid >> 6;
  for (int it = 0; it < 16; ++it) {
    const int t = blockIdx.x * 64 + wave * 16 + it;
    const float* xr = x + (size_t)t * HID;
    float a[NEXP];
#pragma unroll
    for (int e = 0; e < NEXP; ++e) a[e] = 0.f;
    for (int j = 0; j < 16; ++j) {
      const int o = lane + 64 * j;
      const float v = xr[o];
#pragma unroll
      for (int e = 0; e < NEXP; ++e) a[e] += v * sgw[e * HID + o];
    }
#pragma unroll
    for (int off = 32; off > 0; off >>= 1)
#pragma unroll
      for (int e = 0; e < NEXP; ++e) a[e] += __shfl_xor(a[e], off);
    if (lane == 0) {
      float l[NEXP];
#pragma unroll
      for (int e = 0; e < NEXP; ++e) l[e] = a[e] + gb[e];
      int b0 = 0; float v0 = l[0];
#pragma unroll
      for (int e = 1; e < NEXP; ++e) if (l[e] > v0) { b0 = e; v0 = l[e]; }
      int b1i = (b0 == 0) ? 1 : 0; float v1 = l[b1i];
#pragma unroll
      for (int e = 0; e < NEXP; ++e) if (e != b0 && l[e] > v1) { b1i = e; v1 = l[e]; }
      const float e1 = expf(v1 - v0);
      const float inv01 = 1.f / (1.f + e1);
      topk_e[2 * t] = b0; topk_e[2 * t + 1] = b1i;
      topk_w[2 * t] = inv01; topk_w[2 * t + 1] = e1 * inv01;
      atomicAdd(&sCnt[b0], 1); atomicAdd(&sCnt[b1i], 1);
      float s = 0.f, p[NEXP];
#pragma unroll
      for (int e = 0; e < NEXP; ++e) { p[e] = expf(l[e] - v0); s += p[e]; }
      const float invs = 1.f / s;
#pragma unroll
      for (int e = 0; e < NEXP; ++e) atomicAdd(&sProbs[e], p[e] * invs);
    }
  }
  __syncthreads();
  if (tid < NEXP) {
    atomicAdd(&counts[tid], sCnt[tid]);
    atomicAdd(&probs_sum[tid], sProbs[tid]);
  }
}

// ---------------- finalize: padded prefix offsets + l_aux ----------------
__global__ void finalize_kernel(const int* __restrict__ counts,
                                int* __restrict__ cursors,
                                int* __restrict__ offsets,
                                const float* __restrict__ probs_sum,
                                float* __restrict__ laux) {
  if (threadIdx.x == 0) {
    int off = 0;
    for (int e = 0; e < NEXP; ++e) {
      offsets[e] = off;
      off += ((counts[e] + (BM - 1)) / BM) * BM;
      cursors[e] = 0;
    }
    offsets[NEXP] = off;
    float s = 0.f;
    for (int e = 0; e < NEXP; ++e) {
      const float p = probs_sum[e] * (1.f / (float)NTOK);
      s += p * p;
    }
    *laux = (float)NEXP * s;
  }
}

// ---------------- scatter tokens into per-expert pair lists ----------------
__global__ __launch_bounds__(256) void scatter_kernel(
    const int* __restrict__ topk_e, const float* __restrict__ topk_w,
    const int* __restrict__ offsets, int* __restrict__ cursors,
    int* __restrict__ tok_of_pair, float* __restrict__ wt_of_pair) {
  __shared__ int lcnt[NEXP], lbase[NEXP];
  const int tid = threadIdx.x;
  if (tid < NEXP) lcnt[tid] = 0;
  __syncthreads();
  const int t = blockIdx.x * 256 + tid;
  const int e0 = topk_e[2 * t], e1 = topk_e[2 * t + 1];
  const int p0 = atomicAdd(&lcnt[e0], 1);
  const int p1 = atomicAdd(&lcnt[e1], 1);
  __syncthreads();
  if (tid < NEXP) lbase[tid] = atomicAdd(&cursors[tid], lcnt[tid]);
  __syncthreads();
  const int s0 = offsets[e0] + lbase[e0] + p0;
  const int s1 = offsets[e1] + lbase[e1] + p1;
  tok_of_pair[s0] = t; wt_of_pair[s0] = topk_w[2 * t];
  tok_of_pair[s1] = t; wt_of_pair[s1] = topk_w[2 * t + 1];
}

// ---------------- fp32 -> bf16 converts ----------------
__global__ __launch_bounds__(256) void cvt_x_kernel(const float4* __restrict__ src,
                                                    u16x4* __restrict__ dst) {
  const int i = blockIdx.x * 256 + threadIdx.x;  // 2097152 total
  const float4 v = src[i];
  u16x4 o;
  o[0] = bf16_rne(v.x); o[1] = bf16_rne(v.y); o[2] = bf16_rne(v.z); o[3] = bf16_rne(v.w);
  dst[i] = o;
}

__global__ __launch_bounds__(256) void cvt_w1_kernel(const float4* __restrict__ w1,
                                                     u16x4* __restrict__ w1b, int c) {
  const int i = blockIdx.x * 256 + threadIdx.x;  // 2097152 total
  const int e = i >> 18;            // / 262144
  const int r = i & 262143;
  const float4 v = w1[(size_t)e * 1048576 + (size_t)c * 262144 + r];
  u16x4 o;
  o[0] = bf16_rne(v.x); o[1] = bf16_rne(v.y); o[2] = bf16_rne(v.z); o[3] = bf16_rne(v.w);
  w1b[i] = o;
}

__global__ __launch_bounds__(256) void cvt_w2_kernel(const float4* __restrict__ w2,
                                                     u16x4* __restrict__ w2b, int c) {
  const int i = blockIdx.x * 256 + threadIdx.x;  // 2097152 total
  const int e = i >> 18;
  const int r = i & 262143;
  const int o = r >> 8;             // out row
  const int j4 = r & 255;
  const float4 v = w2[(size_t)e * 1048576 + (size_t)o * 1024 + (size_t)c * 256 + j4];
  u16x4 ov;
  ov[0] = bf16_rne(v.x); ov[1] = bf16_rne(v.y); ov[2] = bf16_rne(v.z); ov[3] = bf16_rne(v.w);
  w2b[i] = ov;
}

// ---------------- pass1: h = gelu(x @ w1_chunk^T + b1) ----------------
__global__ __launch_bounds__(256) void pass1_kernel(
    const u16* __restrict__ xb, const u16* __restrict__ w1b,
    const float* __restrict__ b1, const int* __restrict__ tok_of_pair,
    const int* __restrict__ offsets, u16* __restrict__ h, const int chunk) {
  __shared__ u16 As[BM * BK];
  __shared__ u16 Bs[BN * BK];
  const int nt = blockIdx.x, mt = blockIdx.y;
  const int base = mt * BM;
  if (base >= offsets[NEXP]) return;
  int e = 0;
  while (e < NEXP - 1 && base >= offsets[e + 1]) ++e;
  const int tid = threadIdx.x;
  const int lane = tid & 63;
  const int wave = tid >> 6;
  const int wm = wave & 1, wn = wave >> 1;
  const int srow = tid >> 3;
  const int scol = (tid & 7) * 8;
  int tokA[4];
#pragma unroll
  for (int i = 0; i < 4; ++i) tokA[i] = tok_of_pair[base + i * 32 + srow];
  const u16* wB = w1b + (size_t)e * (FCHUNK * HID) + (size_t)(nt * BN) * HID;
  f32x4 acc[4][4];
#pragma unroll
  for (int i = 0; i < 4; ++i)
#pragma unroll
    for (int j = 0; j < 4; ++j) acc[i][j] = (f32x4){0.f, 0.f, 0.f, 0.f};

  for (int k0 = 0; k0 < HID; k0 += BK) {
#pragma unroll
    for (int i = 0; i < 4; ++i) {
      async16(xb + (size_t)tokA[i] * HID + k0 + scol, &As[(i * 32 + srow) * BK + scol]);
      async16(wB + (size_t)(i * 32 + srow) * HID + k0 + scol, &Bs[(i * 32 + srow) * BK + scol]);
    }
    __syncthreads();
#pragma unroll
    for (int s = 0; s < 2; ++s) {
      const int ko = s * 32 + (lane >> 4) * 8;
      bf16x8 af[4], bf[4];
#pragma unroll
      for (int i = 0; i < 4; ++i)
        af[i] = *(const bf16x8*)&As[(wm * 64 + i * 16 + (lane & 15)) * BK + ko];
#pragma unroll
      for (int j = 0; j < 4; ++j)
        bf[j] = *(const bf16x8*)&Bs[(wn * 64 + j * 16 + (lane & 15)) * BK + ko];
#pragma unroll
      for (int i = 0; i < 4; ++i)
#pragma unroll
        for (int j = 0; j < 4; ++j)
          acc[i][j] = __builtin_amdgcn_mfma_f32_16x16x32_bf16(af[i], bf[j], acc[i][j], 0, 0, 0);
    }
    __syncthreads();
  }
  const int nl = lane & 15;
  const int rowq = (lane >> 4) * 4;
  const float* b1e = b1 + (size_t)e * FF + (size_t)chunk * FCHUNK;
#pragma unroll
  for (int i = 0; i < 4; ++i) {
#pragma unroll
    for (int j = 0; j < 4; ++j) {
      const int n = nt * BN + wn * 64 + j * 16 + nl;
      const float bias = b1e[n];
#pragma unroll
      for (int r = 0; r < 4; ++r) {
        const int m = base + wm * 64 + i * 16 + rowq + r;
        float v = acc[i][j][r] + bias;
        v = 0.5f * v * (1.f + erff(v * 0.70710678118654752f));
        h[(size_t)m * FCHUNK + n] = bf16_rne(v);
      }
    }
  }
}

// ---------------- pass2: out[tok] += wt * (h @ w2_chunk^T + b2) ----------------
__global__ __launch_bounds__(256) void pass2_kernel(
    const u16* __restrict__ h, const u16* __restrict__ w2b,
    const float* __restrict__ b2, const int* __restrict__ tok_of_pair,
    const float* __restrict__ wt_of_pair, const int* __restrict__ offsets,
    float* __restrict__ out, const int chunk) {
  __shared__ u16 As[BM * BK];
  __shared__ u16 Bs[BN * BK];
  const int nt = blockIdx.x, mt = blockIdx.y;
  const int base = mt * BM;
  if (base >= offsets[NEXP]) return;
  int e = 0;
  while (e < NEXP - 1 && base >= offsets[e + 1]) ++e;
  const int tid = threadIdx.x;
  const int lane = tid & 63;
  const int wave = tid >> 6;
  const int wm = wave & 1, wn = wave >> 1;
  const int srow = tid >> 3;
  const int scol = (tid & 7) * 8;
  const u16* wB = w2b + (size_t)e * (HID * FCHUNK) + (size_t)(nt * BN) * FCHUNK;
  f32x4 acc[4][4];
#pragma unroll
  for (int i = 0; i < 4; ++i)
#pragma unroll
    for (int j = 0; j < 4; ++j) acc[i][j] = (f32x4){0.f, 0.f, 0.f, 0.f};

  for (int k0 = 0; k0 < FCHUNK; k0 += BK) {
#pragma unroll
    for (int i = 0; i < 4; ++i) {
      async16(h + (size_t)(base + i * 32 + srow) * FCHUNK + k0 + scol,
              &As[(i * 32 + srow) * BK + scol]);
      async16(wB + (size_t)(i * 32 + srow) * FCHUNK + k0 + scol,
              &Bs[(i * 32 + srow) * BK + scol]);
    }
    __syncthreads();
#pragma unroll
    for (int s = 0; s < 2; ++s) {
      const int ko = s * 32 + (lane >> 4) * 8;
      bf16x8 af[4], bf[4];
#pragma unroll
      for (int i = 0; i < 4; ++i)
        af[i] = *(const bf16x8*)&As[(wm * 64 + i * 16 + (lane & 15)) * BK + ko];
#pragma unroll
      for (int j = 0; j < 4; ++j)
        bf[j] = *(const bf16x8*)&Bs[(wn * 64 + j * 16 + (lane & 15)) * BK + ko];
#pragma unroll
      for (int i = 0; i < 4; ++i)
#pragma unroll
        for (int j = 0; j < 4; ++j)
          acc[i][j] = __builtin_amdgcn_mfma_f32_16x16x32_bf16(af[i], bf[j], acc[i][j], 0, 0, 0);
    }
    __syncthreads();
  }
  const int nl = lane & 15;
  const int rowq = (lane >> 4) * 4;
  const float* b2e = b2 + (size_t)e * HID;
#pragma unroll
  for (int i = 0; i < 4; ++i) {
#pragma unroll
    for (int r = 0; r < 4; ++r) {
      const int m = base + wm * 64 + i * 16 + rowq + r;
      const int tokm = tok_of_pair[m];
      const float wtm = wt_of_pair[m];
      float* orow = out + (size_t)tokm * HID;
#pragma unroll
      for (int j = 0; j < 4; ++j) {
        const int o = nt * BN + wn * 64 + j * 16 + nl;
        float v = acc[i][j][r];
        if (chunk == 0) v += b2e[o];
        atomicAdd(&orow[o], wtm * v);
      }
    }
  }
}

extern "C" void kernel_launch(void* const* d_in, const int* in_sizes, int n_in,
                              void* d_out, int out_size, void* d_ws, size_t ws_size,
                              hipStream_t stream) {
  (void)in_sizes; (void)n_in; (void)ws_size;
  const float* x  = (const float*)d_in[0];
  const float* gw = (const float*)d_in[1];
  const float* gb = (const float*)d_in[2];
  const float* w1 = (const float*)d_in[3];
  const float* b1 = (const float*)d_in[4];
  const float* w2 = (const float*)d_in[5];
  const float* b2 = (const float*)d_in[6];
  float* out = (float*)d_out;

  char* ws = (char*)d_ws;
  int*   counts  = (int*)(ws + 0);        // 8
  int*   cursors = (int*)(ws + 32);       // 8
  float* probs   = (float*)(ws + 64);     // 8
  int*   offsets = (int*)(ws + 96);       // 9
  int*   tok     = (int*)(ws + 256);      // MAXPAIR
  float* wt      = (float*)(ws + 256 + 4 * MAXPAIR);          // MAXPAIR
  int*   topk_e  = (int*)(ws + 256 + 8 * MAXPAIR);            // 2*NTOK
  float* topk_w  = (float*)(ws + 256 + 8 * MAXPAIR + 65536);  // 2*NTOK
  u16*   xb      = (u16*)(ws + 270848);
  u16*   w1b     = (u16*)(ws + 270848 + 1u * 16777216u);
  u16*   w2b     = (u16*)(ws + 270848 + 2u * 16777216u);
  u16*   hbuf    = (u16*)(ws + 270848 + 3u * 16777216u);
  // total ws usage: 270848 + 3*16MiB + MAXPAIR*1024*2 = ~86.3 MB

  // zero control region + pair lists (pad slots must have wt=0)
  hipMemsetAsync(ws, 0, 256 + 8 * MAXPAIR, stream);
  hipMemsetAsync(d_out, 0, (size_t)out_size * 4, stream);

  gate_kernel<<<128, 256, 0, stream>>>(x, gw, gb, counts, probs, topk_e, topk_w);
  finalize_kernel<<<1, 64, 0, stream>>>(counts, cursors, offsets, probs,
                                        out + (out_size - 1));
  scatter_kernel<<<32, 256, 0, stream>>>(topk_e, topk_w, offsets, cursors, tok, wt);
  cvt_x_kernel<<<8192, 256, 0, stream>>>((const float4*)x, (u16x4*)xb);

  for (int c = 0; c < NCHUNK; ++c) {
    cvt_w1_kernel<<<8192, 256, 0, stream>>>((const float4*)w1, (u16x4*)w1b, c);
    pass1_kernel<<<dim3(8, 136), 256, 0, stream>>>(xb, w1b, b1, tok, offsets, hbuf, c);
    cvt_w2_kernel<<<8192, 256, 0, stream>>>((const float4*)w2, (u16x4*)w2b, c);
    pass2_kernel<<<dim3(8, 136), 256, 0, stream>>>(hbuf, w2b, b2, tok, wt, offsets, out, c);
  }
}

// Round 2
// 1106.255 us; speedup vs baseline: 1.2467x; 1.2467x over previous
//
#include <hip/hip_runtime.h>
#include <cstdint>
#include <cstddef>

typedef unsigned short u16;
typedef short bf16x8 __attribute__((ext_vector_type(8)));
typedef float f32x4 __attribute__((ext_vector_type(4)));
typedef u16 u16x4 __attribute__((ext_vector_type(4)));

#define NTOK 8192
#define HID 1024
#define NEXP 8
#define FF 4096
#define FCHUNK 1024
#define NCHUNK 4
#define MAXPAIR 17408   // 2*NTOK + NEXP*128 padding headroom
#define BM 128
#define BN 128
#define BK 64

__device__ __forceinline__ u16 bf16_rne(float f) {
  unsigned u = __builtin_bit_cast(unsigned, f);
  return (u16)((u + 0x7FFFu + ((u >> 16) & 1u)) >> 16);
}

__device__ __forceinline__ float gelu_tanh(float v) {
  // 0.5*v*(1+tanh(0.79788456*(v+0.044715 v^3))) = v*(1 - 1/(e^{2u}+1))
  const float u = 0.7978845608028654f * (v + 0.044715f * v * v * v);
  const float e = __expf(2.0f * u);          // inf-safe: e=inf -> v; e=0 -> 0
  return v - v * __frcp_rn(e + 1.0f);
}

__device__ __forceinline__ void async16(const void* g, void* l) {
  __builtin_amdgcn_global_load_lds(
      (const __attribute__((address_space(1))) void*)g,
      (__attribute__((address_space(3))) void*)l, 16, 0, 0);
}

// ---------------- gate: logits, top-2, softmax probs ----------------
__global__ __launch_bounds__(256) void gate_kernel(
    const float* __restrict__ x, const float* __restrict__ gw,
    const float* __restrict__ gb, int* __restrict__ counts,
    float* __restrict__ probs_sum, int* __restrict__ topk_e,
    float* __restrict__ topk_w) {
  __shared__ float sgw[NEXP * HID];
  __shared__ float sProbs[NEXP];
  __shared__ int sCnt[NEXP];
  const int tid = threadIdx.x;
  for (int i = tid; i < NEXP * HID; i += 256) sgw[i] = gw[i];
  if (tid < NEXP) { sProbs[tid] = 0.f; sCnt[tid] = 0; }
  __syncthreads();
  const int lane = tid & 63, wave = tid >> 6;
  for (int it = 0; it < 4; ++it) {
    const int t = blockIdx.x * 16 + wave * 4 + it;
    const float* xr = x + (size_t)t * HID;
    float a[NEXP];
#pragma unroll
    for (int e = 0; e < NEXP; ++e) a[e] = 0.f;
    for (int j = 0; j < 16; ++j) {
      const int o = lane + 64 * j;
      const float v = xr[o];
#pragma unroll
      for (int e = 0; e < NEXP; ++e) a[e] += v * sgw[e * HID + o];
    }
#pragma unroll
    for (int off = 32; off > 0; off >>= 1)
#pragma unroll
      for (int e = 0; e < NEXP; ++e) a[e] += __shfl_xor(a[e], off);
    if (lane == 0) {
      float l[NEXP];
#pragma unroll
      for (int e = 0; e < NEXP; ++e) l[e] = a[e] + gb[e];
      int b0 = 0; float v0 = l[0];
#pragma unroll
      for (int e = 1; e < NEXP; ++e) if (l[e] > v0) { b0 = e; v0 = l[e]; }
      int b1i = (b0 == 0) ? 1 : 0; float v1 = l[b1i];
#pragma unroll
      for (int e = 0; e < NEXP; ++e) if (e != b0 && l[e] > v1) { b1i = e; v1 = l[e]; }
      const float e1 = __expf(v1 - v0);
      const float inv01 = 1.f / (1.f + e1);
      topk_e[2 * t] = b0; topk_e[2 * t + 1] = b1i;
      topk_w[2 * t] = inv01; topk_w[2 * t + 1] = e1 * inv01;
      atomicAdd(&sCnt[b0], 1); atomicAdd(&sCnt[b1i], 1);
      float s = 0.f, p[NEXP];
#pragma unroll
      for (int e = 0; e < NEXP; ++e) { p[e] = __expf(l[e] - v0); s += p[e]; }
      const float invs = 1.f / s;
#pragma unroll
      for (int e = 0; e < NEXP; ++e) atomicAdd(&sProbs[e], p[e] * invs);
    }
  }
  __syncthreads();
  if (tid < NEXP) {
    atomicAdd(&counts[tid], sCnt[tid]);
    atomicAdd(&probs_sum[tid], sProbs[tid]);
  }
}

// ---------------- finalize: padded prefix offsets + l_aux ----------------
__global__ void finalize_kernel(const int* __restrict__ counts,
                                int* __restrict__ cursors,
                                int* __restrict__ offsets,
                                const float* __restrict__ probs_sum,
                                float* __restrict__ laux) {
  if (threadIdx.x == 0) {
    int off = 0;
    for (int e = 0; e < NEXP; ++e) {
      offsets[e] = off;
      off += ((counts[e] + (BM - 1)) / BM) * BM;
      cursors[e] = 0;
    }
    offsets[NEXP] = off;
    float s = 0.f;
    for (int e = 0; e < NEXP; ++e) {
      const float p = probs_sum[e] * (1.f / (float)NTOK);
      s += p * p;
    }
    *laux = (float)NEXP * s;
  }
}

// ---------------- scatter tokens into per-expert pair lists ----------------
__global__ __launch_bounds__(256) void scatter_kernel(
    const int* __restrict__ topk_e, const float* __restrict__ topk_w,
    const int* __restrict__ offsets, int* __restrict__ cursors,
    int* __restrict__ tok_of_pair, float* __restrict__ wt_of_pair,
    int* __restrict__ slot_of_tok) {
  __shared__ int lcnt[NEXP], lbase[NEXP];
  const int tid = threadIdx.x;
  if (tid < NEXP) lcnt[tid] = 0;
  __syncthreads();
  const int t = blockIdx.x * 256 + tid;
  const int e0 = topk_e[2 * t], e1 = topk_e[2 * t + 1];
  const int p0 = atomicAdd(&lcnt[e0], 1);
  const int p1 = atomicAdd(&lcnt[e1], 1);
  __syncthreads();
  if (tid < NEXP) lbase[tid] = atomicAdd(&cursors[tid], lcnt[tid]);
  __syncthreads();
  const int s0 = offsets[e0] + lbase[e0] + p0;
  const int s1 = offsets[e1] + lbase[e1] + p1;
  tok_of_pair[s0] = t; wt_of_pair[s0] = topk_w[2 * t];
  tok_of_pair[s1] = t; wt_of_pair[s1] = topk_w[2 * t + 1];
  slot_of_tok[2 * t] = s0; slot_of_tok[2 * t + 1] = s1;
}

// ---------------- fp32 -> bf16 converts ----------------
__global__ __launch_bounds__(256) void cvt_x_kernel(const float4* __restrict__ src,
                                                    u16x4* __restrict__ dst) {
  const int i = blockIdx.x * 256 + threadIdx.x;  // 2097152 total
  const float4 v = src[i];
  u16x4 o;
  o[0] = bf16_rne(v.x); o[1] = bf16_rne(v.y); o[2] = bf16_rne(v.z); o[3] = bf16_rne(v.w);
  dst[i] = o;
}

__global__ __launch_bounds__(256) void cvt_w1_kernel(const float4* __restrict__ w1,
                                                     u16x4* __restrict__ w1b, int c) {
  const int i = blockIdx.x * 256 + threadIdx.x;  // 2097152 total
  const int e = i >> 18;            // / 262144
  const int r = i & 262143;
  const float4 v = w1[(size_t)e * 1048576 + (size_t)c * 262144 + r];
  u16x4 o;
  o[0] = bf16_rne(v.x); o[1] = bf16_rne(v.y); o[2] = bf16_rne(v.z); o[3] = bf16_rne(v.w);
  w1b[i] = o;
}

__global__ __launch_bounds__(256) void cvt_w2_kernel(const float4* __restrict__ w2,
                                                     u16x4* __restrict__ w2b, int c) {
  const int i = blockIdx.x * 256 + threadIdx.x;  // 2097152 total
  const int e = i >> 18;
  const int r = i & 262143;
  const int o = r >> 8;             // out row
  const int j4 = r & 255;
  const float4 v = w2[(size_t)e * 1048576 + (size_t)o * 1024 + (size_t)c * 256 + j4];
  u16x4 ov;
  ov[0] = bf16_rne(v.x); ov[1] = bf16_rne(v.y); ov[2] = bf16_rne(v.z); ov[3] = bf16_rne(v.w);
  w2b[i] = ov;
}

// ---------------- pass1: h = gelu(x @ w1_chunk^T + b1) ----------------
__global__ __launch_bounds__(256) void pass1_kernel(
    const u16* __restrict__ xb, const u16* __restrict__ w1b,
    const float* __restrict__ b1, const int* __restrict__ tok_of_pair,
    const int* __restrict__ offsets, u16* __restrict__ h, const int chunk) {
  __shared__ u16 As[BM * BK];
  __shared__ u16 Bs[BN * BK];
  const int nt = blockIdx.x, mt = blockIdx.y;
  const int base = mt * BM;
  if (base >= offsets[NEXP]) return;
  int e = 0;
  while (e < NEXP - 1 && base >= offsets[e + 1]) ++e;
  const int tid = threadIdx.x;
  const int lane = tid & 63;
  const int wave = tid >> 6;
  const int wm = wave & 1, wn = wave >> 1;
  const int srow = tid >> 3;
  const int scol = (tid & 7) * 8;
  int tokA[4];
#pragma unroll
  for (int i = 0; i < 4; ++i) tokA[i] = tok_of_pair[base + i * 32 + srow];
  const u16* wB = w1b + (size_t)e * (FCHUNK * HID) + (size_t)(nt * BN) * HID;
  f32x4 acc[4][4];
#pragma unroll
  for (int i = 0; i < 4; ++i)
#pragma unroll
    for (int j = 0; j < 4; ++j) acc[i][j] = (f32x4){0.f, 0.f, 0.f, 0.f};

  for (int k0 = 0; k0 < HID; k0 += BK) {
#pragma unroll
    for (int i = 0; i < 4; ++i) {
      async16(xb + (size_t)tokA[i] * HID + k0 + scol, &As[(i * 32 + srow) * BK + scol]);
      async16(wB + (size_t)(i * 32 + srow) * HID + k0 + scol, &Bs[(i * 32 + srow) * BK + scol]);
    }
    __syncthreads();
#pragma unroll
    for (int s = 0; s < 2; ++s) {
      const int ko = s * 32 + (lane >> 4) * 8;
      bf16x8 af[4], bf[4];
#pragma unroll
      for (int i = 0; i < 4; ++i)
        af[i] = *(const bf16x8*)&As[(wm * 64 + i * 16 + (lane & 15)) * BK + ko];
#pragma unroll
      for (int j = 0; j < 4; ++j)
        bf[j] = *(const bf16x8*)&Bs[(wn * 64 + j * 16 + (lane & 15)) * BK + ko];
#pragma unroll
      for (int i = 0; i < 4; ++i)
#pragma unroll
        for (int j = 0; j < 4; ++j)
          acc[i][j] = __builtin_amdgcn_mfma_f32_16x16x32_bf16(af[i], bf[j], acc[i][j], 0, 0, 0);
    }
    __syncthreads();
  }
  const int nl = lane & 15;
  const int rowq = (lane >> 4) * 4;
  const float* b1e = b1 + (size_t)e * FF + (size_t)chunk * FCHUNK;
#pragma unroll
  for (int i = 0; i < 4; ++i) {
#pragma unroll
    for (int j = 0; j < 4; ++j) {
      const int n = nt * BN + wn * 64 + j * 16 + nl;
      const float bias = b1e[n];
#pragma unroll
      for (int r = 0; r < 4; ++r) {
        const int m = base + wm * 64 + i * 16 + rowq + r;
        h[(size_t)m * FCHUNK + n] = bf16_rne(gelu_tanh(acc[i][j][r] + bias));
      }
    }
  }
}

// ---------------- pass2: ypair[m] += h @ w2_chunk^T (YP) or atomic out ----------------
template <bool YP>
__global__ __launch_bounds__(256) void pass2_kernel(
    const u16* __restrict__ h, const u16* __restrict__ w2b,
    const float* __restrict__ b2, const int* __restrict__ tok_of_pair,
    const float* __restrict__ wt_of_pair, const int* __restrict__ offsets,
    float* __restrict__ ypair, float* __restrict__ out, const int chunk) {
  __shared__ u16 As[BM * BK];
  __shared__ u16 Bs[BN * BK];
  const int nt = blockIdx.x, mt = blockIdx.y;
  const int base = mt * BM;
  if (base >= offsets[NEXP]) return;
  int e = 0;
  while (e < NEXP - 1 && base >= offsets[e + 1]) ++e;
  const int tid = threadIdx.x;
  const int lane = tid & 63;
  const int wave = tid >> 6;
  const int wm = wave & 1, wn = wave >> 1;
  const int srow = tid >> 3;
  const int scol = (tid & 7) * 8;
  const u16* wB = w2b + (size_t)e * (HID * FCHUNK) + (size_t)(nt * BN) * FCHUNK;
  f32x4 acc[4][4];
#pragma unroll
  for (int i = 0; i < 4; ++i)
#pragma unroll
    for (int j = 0; j < 4; ++j) acc[i][j] = (f32x4){0.f, 0.f, 0.f, 0.f};

  for (int k0 = 0; k0 < FCHUNK; k0 += BK) {
#pragma unroll
    for (int i = 0; i < 4; ++i) {
      async16(h + (size_t)(base + i * 32 + srow) * FCHUNK + k0 + scol,
              &As[(i * 32 + srow) * BK + scol]);
      async16(wB + (size_t)(i * 32 + srow) * FCHUNK + k0 + scol,
              &Bs[(i * 32 + srow) * BK + scol]);
    }
    __syncthreads();
#pragma unroll
    for (int s = 0; s < 2; ++s) {
      const int ko = s * 32 + (lane >> 4) * 8;
      bf16x8 af[4], bf[4];
#pragma unroll
      for (int i = 0; i < 4; ++i)
        af[i] = *(const bf16x8*)&As[(wm * 64 + i * 16 + (lane & 15)) * BK + ko];
#pragma unroll
      for (int j = 0; j < 4; ++j)
        bf[j] = *(const bf16x8*)&Bs[(wn * 64 + j * 16 + (lane & 15)) * BK + ko];
#pragma unroll
      for (int i = 0; i < 4; ++i)
#pragma unroll
        for (int j = 0; j < 4; ++j)
          acc[i][j] = __builtin_amdgcn_mfma_f32_16x16x32_bf16(af[i], bf[j], acc[i][j], 0, 0, 0);
    }
    __syncthreads();
  }
  const int nl = lane & 15;
  const int rowq = (lane >> 4) * 4;
  if (YP) {
    // block exclusively owns rows [base+..] x cols [nt*BN..): race-free RMW
#pragma unroll
    for (int i = 0; i < 4; ++i) {
#pragma unroll
      for (int r = 0; r < 4; ++r) {
        const int m = base + wm * 64 + i * 16 + rowq + r;
        float* yrow = ypair + (size_t)m * HID;
#pragma unroll
        for (int j = 0; j < 4; ++j) {
          const int o = nt * BN + wn * 64 + j * 16 + nl;
          float v = acc[i][j][r];
          if (chunk != 0) v += yrow[o];
          yrow[o] = v;
        }
      }
    }
  } else {
    const float* b2e = b2 + (size_t)e * HID;
#pragma unroll
    for (int i = 0; i < 4; ++i) {
#pragma unroll
      for (int r = 0; r < 4; ++r) {
        const int m = base + wm * 64 + i * 16 + rowq + r;
        const int tokm = tok_of_pair[m];
        const float wtm = wt_of_pair[m];
        float* orow = out + (size_t)tokm * HID;
#pragma unroll
        for (int j = 0; j < 4; ++j) {
          const int o = nt * BN + wn * 64 + j * 16 + nl;
          float v = acc[i][j][r];
          if (chunk == 0) v += b2e[o];
          atomicAdd(&orow[o], wtm * v);
        }
      }
    }
  }
}

// ---------------- combine: out[t] = w0*(y[s0]+b2[e0]) + w1*(y[s1]+b2[e1]) ----------------
__global__ __launch_bounds__(256) void combine_kernel(
    const float* __restrict__ ypair, const int* __restrict__ slot_of_tok,
    const int* __restrict__ topk_e, const float* __restrict__ topk_w,
    const float* __restrict__ b2, float* __restrict__ out) {
  const int t = blockIdx.x;
  const int tid = threadIdx.x;
  const int s0 = slot_of_tok[2 * t], s1 = slot_of_tok[2 * t + 1];
  const int e0 = topk_e[2 * t], e1 = topk_e[2 * t + 1];
  const float w0 = topk_w[2 * t], w1v = topk_w[2 * t + 1];
  const float4 y0 = ((const float4*)(ypair + (size_t)s0 * HID))[tid];
  const float4 y1 = ((const float4*)(ypair + (size_t)s1 * HID))[tid];
  const float4 c0 = ((const float4*)(b2 + (size_t)e0 * HID))[tid];
  const float4 c1 = ((const float4*)(b2 + (size_t)e1 * HID))[tid];
  float4 o;
  o.x = w0 * (y0.x + c0.x) + w1v * (y1.x + c1.x);
  o.y = w0 * (y0.y + c0.y) + w1v * (y1.y + c1.y);
  o.z = w0 * (y0.z + c0.z) + w1v * (y1.z + c1.z);
  o.w = w0 * (y0.w + c0.w) + w1v * (y1.w + c1.w);
  ((float4*)(out + (size_t)t * HID))[tid] = o;
}

extern "C" void kernel_launch(void* const* d_in, const int* in_sizes, int n_in,
                              void* d_out, int out_size, void* d_ws, size_t ws_size,
                              hipStream_t stream) {
  (void)in_sizes; (void)n_in;
  const float* x  = (const float*)d_in[0];
  const float* gw = (const float*)d_in[1];
  const float* gb = (const float*)d_in[2];
  const float* w1 = (const float*)d_in[3];
  const float* b1 = (const float*)d_in[4];
  const float* w2 = (const float*)d_in[5];
  const float* b2 = (const float*)d_in[6];
  float* out = (float*)d_out;

  char* ws = (char*)d_ws;
  // control region
  int*   counts  = (int*)(ws + 0);         // 8
  int*   cursors = (int*)(ws + 32);        // 8
  float* probs   = (float*)(ws + 64);      // 8
  int*   offsets = (int*)(ws + 96);        // 9
  int*   tok     = (int*)(ws + 256);                       // MAXPAIR ints
  float* wt      = (float*)(ws + 256 + 4 * MAXPAIR);       // MAXPAIR  -> ends 139520
  int*   topk_e  = (int*)(ws + 139520);                    // 2*NTOK   -> 205056
  float* topk_w  = (float*)(ws + 205056);                  // 2*NTOK   -> 270592
  int*   slot    = (int*)(ws + 270592);                    // 2*NTOK   -> 336128
  const size_t OFF_XB  = 336128;
  const size_t OFF_W1B = OFF_XB + 16777216;                // 17113344
  const size_t OFF_W2B = OFF_W1B + 16777216;               // 33890560
  const size_t OFF_H   = OFF_W2B + 16777216;               // 50667776
  const size_t OFF_YP  = OFF_H + (size_t)MAXPAIR * FCHUNK * 2;   // 86319360 (proven-safe bound)
  const size_t WS_BIG  = OFF_YP + (size_t)MAXPAIR * HID * 4;     // 157622528
  u16*   xb    = (u16*)(ws + OFF_XB);
  u16*   w1b   = (u16*)(ws + OFF_W1B);
  u16*   w2b   = (u16*)(ws + OFF_W2B);
  u16*   hbuf  = (u16*)(ws + OFF_H);
  float* ypair = (float*)(ws + OFF_YP);
  const bool big = ws_size >= WS_BIG;

  // zero control + pair lists (pad slots need tok=0 valid / wt=0 for atomic path)
  hipMemsetAsync(ws, 0, 139520, stream);
  if (!big) hipMemsetAsync(d_out, 0, (size_t)out_size * 4, stream);

  gate_kernel<<<512, 256, 0, stream>>>(x, gw, gb, counts, probs, topk_e, topk_w);
  finalize_kernel<<<1, 64, 0, stream>>>(counts, cursors, offsets, probs,
                                        out + (out_size - 1));
  scatter_kernel<<<32, 256, 0, stream>>>(topk_e, topk_w, offsets, cursors, tok, wt, slot);
  cvt_x_kernel<<<8192, 256, 0, stream>>>((const float4*)x, (u16x4*)xb);

  for (int c = 0; c < NCHUNK; ++c) {
    cvt_w1_kernel<<<8192, 256, 0, stream>>>((const float4*)w1, (u16x4*)w1b, c);
    pass1_kernel<<<dim3(8, 136), 256, 0, stream>>>(xb, w1b, b1, tok, offsets, hbuf, c);
    cvt_w2_kernel<<<8192, 256, 0, stream>>>((const float4*)w2, (u16x4*)w2b, c);
    if (big)
      pass2_kernel<true><<<dim3(8, 136), 256, 0, stream>>>(hbuf, w2b, b2, tok, wt,
                                                           offsets, ypair, out, c);
    else
      pass2_kernel<false><<<dim3(8, 136), 256, 0, stream>>>(hbuf, w2b, b2, tok, wt,
                                                            offsets, ypair, out, c);
  }
  if (big)
    combine_kernel<<<8192, 256, 0, stream>>>(ypair, slot, topk_e, topk_w, b2, out);
}

// Round 3
// 948.957 us; speedup vs baseline: 1.4533x; 1.1658x over previous
//
#include <hip/hip_runtime.h>
#include <cstdint>
#include <cstddef>

typedef unsigned short u16;
typedef short bf16x8 __attribute__((ext_vector_type(8)));
typedef float f32x4 __attribute__((ext_vector_type(4)));
typedef u16 u16x4 __attribute__((ext_vector_type(4)));

#define NTOK 8192
#define HID 1024
#define NEXP 8
#define FF 4096
#define FCHUNK 1024
#define NCHUNK 4
#define MAXPAIR 17408   // 2*NTOK + NEXP*128 padding headroom
#define BM 128
#define BN 128
#define BK 64

__device__ __forceinline__ u16 bf16_rne(float f) {
  unsigned u = __builtin_bit_cast(unsigned, f);
  return (u16)((u + 0x7FFFu + ((u >> 16) & 1u)) >> 16);
}

__device__ __forceinline__ float gelu_tanh(float v) {
  const float u = 0.7978845608028654f * (v + 0.044715f * v * v * v);
  const float e = __expf(2.0f * u);          // inf-safe: e=inf -> v; e=0 -> 0
  return v - v * __frcp_rn(e + 1.0f);
}

__device__ __forceinline__ void async16(const void* g, void* l) {
  __builtin_amdgcn_global_load_lds(
      (const __attribute__((address_space(1))) void*)g,
      (__attribute__((address_space(3))) void*)l, 16, 0, 0);
}

// ---------------- gate: logits, top-2, softmax probs ----------------
__global__ __launch_bounds__(256) void gate_kernel(
    const float* __restrict__ x, const float* __restrict__ gw,
    const float* __restrict__ gb, int* __restrict__ counts,
    float* __restrict__ probs_sum, int* __restrict__ topk_e,
    float* __restrict__ topk_w) {
  __shared__ float sgw[NEXP * HID];
  __shared__ float sProbs[NEXP];
  __shared__ int sCnt[NEXP];
  const int tid = threadIdx.x;
  for (int i = tid; i < NEXP * HID; i += 256) sgw[i] = gw[i];
  if (tid < NEXP) { sProbs[tid] = 0.f; sCnt[tid] = 0; }
  __syncthreads();
  const int lane = tid & 63, wave = tid >> 6;
  for (int it = 0; it < 4; ++it) {
    const int t = blockIdx.x * 16 + wave * 4 + it;
    const float* xr = x + (size_t)t * HID;
    float a[NEXP];
#pragma unroll
    for (int e = 0; e < NEXP; ++e) a[e] = 0.f;
    for (int j = 0; j < 16; ++j) {
      const int o = lane + 64 * j;
      const float v = xr[o];
#pragma unroll
      for (int e = 0; e < NEXP; ++e) a[e] += v * sgw[e * HID + o];
    }
#pragma unroll
    for (int off = 32; off > 0; off >>= 1)
#pragma unroll
      for (int e = 0; e < NEXP; ++e) a[e] += __shfl_xor(a[e], off);
    if (lane == 0) {
      float l[NEXP];
#pragma unroll
      for (int e = 0; e < NEXP; ++e) l[e] = a[e] + gb[e];
      int b0 = 0; float v0 = l[0];
#pragma unroll
      for (int e = 1; e < NEXP; ++e) if (l[e] > v0) { b0 = e; v0 = l[e]; }
      int b1i = (b0 == 0) ? 1 : 0; float v1 = l[b1i];
#pragma unroll
      for (int e = 0; e < NEXP; ++e) if (e != b0 && l[e] > v1) { b1i = e; v1 = l[e]; }
      const float e1 = __expf(v1 - v0);
      const float inv01 = 1.f / (1.f + e1);
      topk_e[2 * t] = b0; topk_e[2 * t + 1] = b1i;
      topk_w[2 * t] = inv01; topk_w[2 * t + 1] = e1 * inv01;
      atomicAdd(&sCnt[b0], 1); atomicAdd(&sCnt[b1i], 1);
      float s = 0.f, p[NEXP];
#pragma unroll
      for (int e = 0; e < NEXP; ++e) { p[e] = __expf(l[e] - v0); s += p[e]; }
      const float invs = 1.f / s;
#pragma unroll
      for (int e = 0; e < NEXP; ++e) atomicAdd(&sProbs[e], p[e] * invs);
    }
  }
  __syncthreads();
  if (tid < NEXP) {
    atomicAdd(&counts[tid], sCnt[tid]);
    atomicAdd(&probs_sum[tid], sProbs[tid]);
  }
}

// ---------------- finalize: padded prefix offsets + l_aux ----------------
__global__ void finalize_kernel(const int* __restrict__ counts,
                                int* __restrict__ cursors,
                                int* __restrict__ offsets,
                                const float* __restrict__ probs_sum,
                                float* __restrict__ laux) {
  if (threadIdx.x == 0) {
    int off = 0;
    for (int e = 0; e < NEXP; ++e) {
      offsets[e] = off;
      off += ((counts[e] + (BM - 1)) / BM) * BM;
      cursors[e] = 0;
    }
    offsets[NEXP] = off;
    float s = 0.f;
    for (int e = 0; e < NEXP; ++e) {
      const float p = probs_sum[e] * (1.f / (float)NTOK);
      s += p * p;
    }
    *laux = (float)NEXP * s;
  }
}

// ---------------- scatter tokens into per-expert pair lists ----------------
__global__ __launch_bounds__(256) void scatter_kernel(
    const int* __restrict__ topk_e, const float* __restrict__ topk_w,
    const int* __restrict__ offsets, int* __restrict__ cursors,
    int* __restrict__ tok_of_pair, float* __restrict__ wt_of_pair,
    int* __restrict__ slot_of_tok) {
  __shared__ int lcnt[NEXP], lbase[NEXP];
  const int tid = threadIdx.x;
  if (tid < NEXP) lcnt[tid] = 0;
  __syncthreads();
  const int t = blockIdx.x * 256 + tid;
  const int e0 = topk_e[2 * t], e1 = topk_e[2 * t + 1];
  const int p0 = atomicAdd(&lcnt[e0], 1);
  const int p1 = atomicAdd(&lcnt[e1], 1);
  __syncthreads();
  if (tid < NEXP) lbase[tid] = atomicAdd(&cursors[tid], lcnt[tid]);
  __syncthreads();
  const int s0 = offsets[e0] + lbase[e0] + p0;
  const int s1 = offsets[e1] + lbase[e1] + p1;
  tok_of_pair[s0] = t; wt_of_pair[s0] = topk_w[2 * t];
  tok_of_pair[s1] = t; wt_of_pair[s1] = topk_w[2 * t + 1];
  slot_of_tok[2 * t] = s0; slot_of_tok[2 * t + 1] = s1;
}

// ---------------- fp32 -> bf16 streaming convert ----------------
__global__ __launch_bounds__(256) void stream_cvt_kernel(const float4* __restrict__ src,
                                                         u16x4* __restrict__ dst) {
  const int i = blockIdx.x * 256 + threadIdx.x;
  const float4 v = src[i];
  u16x4 o;
  o[0] = bf16_rne(v.x); o[1] = bf16_rne(v.y); o[2] = bf16_rne(v.z); o[3] = bf16_rne(v.w);
  dst[i] = o;
}

// chunked converts (fallback path)
__global__ __launch_bounds__(256) void cvt_w1_kernel(const float4* __restrict__ w1,
                                                     u16x4* __restrict__ w1b, int c) {
  const int i = blockIdx.x * 256 + threadIdx.x;  // 2097152 total
  const int e = i >> 18;
  const int r = i & 262143;
  const float4 v = w1[(size_t)e * 1048576 + (size_t)c * 262144 + r];
  u16x4 o;
  o[0] = bf16_rne(v.x); o[1] = bf16_rne(v.y); o[2] = bf16_rne(v.z); o[3] = bf16_rne(v.w);
  w1b[i] = o;
}

__global__ __launch_bounds__(256) void cvt_w2_kernel(const float4* __restrict__ w2,
                                                     u16x4* __restrict__ w2b, int c) {
  const int i = blockIdx.x * 256 + threadIdx.x;  // 2097152 total
  const int e = i >> 18;
  const int r = i & 262143;
  const int o = r >> 8;
  const int j4 = r & 255;
  const float4 v = w2[(size_t)e * 1048576 + (size_t)o * 1024 + (size_t)c * 256 + j4];
  u16x4 ov;
  ov[0] = bf16_rne(v.x); ov[1] = bf16_rne(v.y); ov[2] = bf16_rne(v.z); ov[3] = bf16_rne(v.w);
  w2b[i] = ov;
}

// ---------------- pass1: h = gelu(x @ w1^T + b1), N = ffN ----------------
__global__ __launch_bounds__(256) void pass1_kernel(
    const u16* __restrict__ xb, const u16* __restrict__ w1b,
    const float* __restrict__ b1, const int* __restrict__ tok_of_pair,
    const int* __restrict__ offsets, u16* __restrict__ h, const int ffN,
    const int chunk) {
  __shared__ u16 As[BM * BK];
  __shared__ u16 Bs[BN * BK];
  const int nt = blockIdx.x, mt = blockIdx.y;
  const int base = mt * BM;
  if (base >= offsets[NEXP]) return;
  int e = 0;
  while (e < NEXP - 1 && base >= offsets[e + 1]) ++e;
  const int tid = threadIdx.x;
  const int lane = tid & 63;
  const int wave = tid >> 6;
  const int wm = wave & 1, wn = wave >> 1;
  const int srow = tid >> 3;
  const int scol = (tid & 7) * 8;
  int tokA[4];
#pragma unroll
  for (int i = 0; i < 4; ++i) tokA[i] = tok_of_pair[base + i * 32 + srow];
  const u16* wB = w1b + (size_t)e * ((size_t)ffN * HID) + (size_t)(nt * BN) * HID;
  f32x4 acc[4][4];
#pragma unroll
  for (int i = 0; i < 4; ++i)
#pragma unroll
    for (int j = 0; j < 4; ++j) acc[i][j] = (f32x4){0.f, 0.f, 0.f, 0.f};

  for (int k0 = 0; k0 < HID; k0 += BK) {
#pragma unroll
    for (int i = 0; i < 4; ++i) {
      async16(xb + (size_t)tokA[i] * HID + k0 + scol, &As[(i * 32 + srow) * BK + scol]);
      async16(wB + (size_t)(i * 32 + srow) * HID + k0 + scol, &Bs[(i * 32 + srow) * BK + scol]);
    }
    __syncthreads();
#pragma unroll
    for (int s = 0; s < 2; ++s) {
      const int ko = s * 32 + (lane >> 4) * 8;
      bf16x8 af[4], bf[4];
#pragma unroll
      for (int i = 0; i < 4; ++i)
        af[i] = *(const bf16x8*)&As[(wm * 64 + i * 16 + (lane & 15)) * BK + ko];
#pragma unroll
      for (int j = 0; j < 4; ++j)
        bf[j] = *(const bf16x8*)&Bs[(wn * 64 + j * 16 + (lane & 15)) * BK + ko];
#pragma unroll
      for (int i = 0; i < 4; ++i)
#pragma unroll
        for (int j = 0; j < 4; ++j)
          acc[i][j] = __builtin_amdgcn_mfma_f32_16x16x32_bf16(af[i], bf[j], acc[i][j], 0, 0, 0);
    }
    __syncthreads();
  }
  const int nl = lane & 15;
  const int rowq = (lane >> 4) * 4;
  const float* b1e = b1 + (size_t)e * FF + (size_t)chunk * FCHUNK;
#pragma unroll
  for (int i = 0; i < 4; ++i) {
#pragma unroll
    for (int j = 0; j < 4; ++j) {
      const int n = nt * BN + wn * 64 + j * 16 + nl;
      const float bias = b1e[n];
#pragma unroll
      for (int r = 0; r < 4; ++r) {
        const int m = base + wm * 64 + i * 16 + rowq + r;
        h[(size_t)m * ffN + n] = bf16_rne(gelu_tanh(acc[i][j][r] + bias));
      }
    }
  }
}

// ---------------- pass2: ypair[m] += h @ w2^T (YP) or atomic out, K = kTot ----
template <bool YP>
__global__ __launch_bounds__(256) void pass2_kernel(
    const u16* __restrict__ h, const u16* __restrict__ w2b,
    const float* __restrict__ b2, const int* __restrict__ tok_of_pair,
    const float* __restrict__ wt_of_pair, const int* __restrict__ offsets,
    float* __restrict__ ypair, float* __restrict__ out, const int kTot,
    const int chunk) {
  __shared__ u16 As[BM * BK];
  __shared__ u16 Bs[BN * BK];
  const int nt = blockIdx.x, mt = blockIdx.y;
  const int base = mt * BM;
  if (base >= offsets[NEXP]) return;
  int e = 0;
  while (e < NEXP - 1 && base >= offsets[e + 1]) ++e;
  const int tid = threadIdx.x;
  const int lane = tid & 63;
  const int wave = tid >> 6;
  const int wm = wave & 1, wn = wave >> 1;
  const int srow = tid >> 3;
  const int scol = (tid & 7) * 8;
  const u16* wB = w2b + (size_t)e * ((size_t)HID * kTot) + (size_t)(nt * BN) * kTot;
  f32x4 acc[4][4];
#pragma unroll
  for (int i = 0; i < 4; ++i)
#pragma unroll
    for (int j = 0; j < 4; ++j) acc[i][j] = (f32x4){0.f, 0.f, 0.f, 0.f};

  for (int k0 = 0; k0 < kTot; k0 += BK) {
#pragma unroll
    for (int i = 0; i < 4; ++i) {
      async16(h + (size_t)(base + i * 32 + srow) * kTot + k0 + scol,
              &As[(i * 32 + srow) * BK + scol]);
      async16(wB + (size_t)(i * 32 + srow) * kTot + k0 + scol,
              &Bs[(i * 32 + srow) * BK + scol]);
    }
    __syncthreads();
#pragma unroll
    for (int s = 0; s < 2; ++s) {
      const int ko = s * 32 + (lane >> 4) * 8;
      bf16x8 af[4], bf[4];
#pragma unroll
      for (int i = 0; i < 4; ++i)
        af[i] = *(const bf16x8*)&As[(wm * 64 + i * 16 + (lane & 15)) * BK + ko];
#pragma unroll
      for (int j = 0; j < 4; ++j)
        bf[j] = *(const bf16x8*)&Bs[(wn * 64 + j * 16 + (lane & 15)) * BK + ko];
#pragma unroll
      for (int i = 0; i < 4; ++i)
#pragma unroll
        for (int j = 0; j < 4; ++j)
          acc[i][j] = __builtin_amdgcn_mfma_f32_16x16x32_bf16(af[i], bf[j], acc[i][j], 0, 0, 0);
    }
    __syncthreads();
  }
  const int nl = lane & 15;
  const int rowq = (lane >> 4) * 4;
  if (YP) {
#pragma unroll
    for (int i = 0; i < 4; ++i) {
#pragma unroll
      for (int r = 0; r < 4; ++r) {
        const int m = base + wm * 64 + i * 16 + rowq + r;
        float* yrow = ypair + (size_t)m * HID;
#pragma unroll
        for (int j = 0; j < 4; ++j) {
          const int o = nt * BN + wn * 64 + j * 16 + nl;
          float v = acc[i][j][r];
          if (chunk != 0) v += yrow[o];
          yrow[o] = v;
        }
      }
    }
  } else {
    const float* b2e = b2 + (size_t)e * HID;
#pragma unroll
    for (int i = 0; i < 4; ++i) {
#pragma unroll
      for (int r = 0; r < 4; ++r) {
        const int m = base + wm * 64 + i * 16 + rowq + r;
        const int tokm = tok_of_pair[m];
        const float wtm = wt_of_pair[m];
        float* orow = out + (size_t)tokm * HID;
#pragma unroll
        for (int j = 0; j < 4; ++j) {
          const int o = nt * BN + wn * 64 + j * 16 + nl;
          float v = acc[i][j][r];
          if (chunk == 0) v += b2e[o];
          atomicAdd(&orow[o], wtm * v);
        }
      }
    }
  }
}

// ---------------- combine: out[t] = w0*(y[s0]+b2[e0]) + w1*(y[s1]+b2[e1]) ----
__global__ __launch_bounds__(256) void combine_kernel(
    const float* __restrict__ ypair, const int* __restrict__ slot_of_tok,
    const int* __restrict__ topk_e, const float* __restrict__ topk_w,
    const float* __restrict__ b2, float* __restrict__ out) {
  const int t = blockIdx.x;
  const int tid = threadIdx.x;
  const int s0 = slot_of_tok[2 * t], s1 = slot_of_tok[2 * t + 1];
  const int e0 = topk_e[2 * t], e1 = topk_e[2 * t + 1];
  const float w0 = topk_w[2 * t], w1v = topk_w[2 * t + 1];
  const float4 y0 = ((const float4*)(ypair + (size_t)s0 * HID))[tid];
  const float4 y1 = ((const float4*)(ypair + (size_t)s1 * HID))[tid];
  const float4 c0 = ((const float4*)(b2 + (size_t)e0 * HID))[tid];
  const float4 c1 = ((const float4*)(b2 + (size_t)e1 * HID))[tid];
  float4 o;
  o.x = w0 * (y0.x + c0.x) + w1v * (y1.x + c1.x);
  o.y = w0 * (y0.y + c0.y) + w1v * (y1.y + c1.y);
  o.z = w0 * (y0.z + c0.z) + w1v * (y1.z + c1.z);
  o.w = w0 * (y0.w + c0.w) + w1v * (y1.w + c1.w);
  ((float4*)(out + (size_t)t * HID))[tid] = o;
}

extern "C" void kernel_launch(void* const* d_in, const int* in_sizes, int n_in,
                              void* d_out, int out_size, void* d_ws, size_t ws_size,
                              hipStream_t stream) {
  (void)in_sizes; (void)n_in;
  const float* x  = (const float*)d_in[0];
  const float* gw = (const float*)d_in[1];
  const float* gb = (const float*)d_in[2];
  const float* w1 = (const float*)d_in[3];
  const float* b1 = (const float*)d_in[4];
  const float* w2 = (const float*)d_in[5];
  const float* b2 = (const float*)d_in[6];
  float* out = (float*)d_out;

  char* ws = (char*)d_ws;
  // control region (shared by all paths)
  int*   counts  = (int*)(ws + 0);
  int*   cursors = (int*)(ws + 32);
  float* probs   = (float*)(ws + 64);
  int*   offsets = (int*)(ws + 96);
  int*   tok     = (int*)(ws + 256);                       // MAXPAIR ints
  float* wt      = (float*)(ws + 256 + 4 * MAXPAIR);       // -> ends 139520
  int*   topk_e  = (int*)(ws + 139520);                    // -> 205056
  float* topk_w  = (float*)(ws + 205056);                  // -> 270592
  int*   slot    = (int*)(ws + 270592);                    // -> 336128
  const size_t OFF_XB = 336128;
  u16* xb = (u16*)(ws + OFF_XB);                           // 16,777,216 B

  // ---- full-FF layout ----
  const size_t OFF_W1B_F = OFF_XB + 16777216;              // 17,113,344
  const size_t OFF_W2B_F = OFF_W1B_F + 67108864;           // 84,222,208
  const size_t OFF_H_F   = OFF_W2B_F + 67108864;           // 151,331,072
  const size_t OFF_YP_F  = OFF_H_F + (size_t)MAXPAIR * FF * 2;    // 293,937,408
  const size_t WS_FULL_AT = OFF_YP_F;                             // full, atomic epilogue
  const size_t WS_FULL_YP = OFF_YP_F + (size_t)MAXPAIR * HID * 4; // 365,240,576

  // ---- chunked layout (proven R1) ----
  const size_t OFF_W1B_C = OFF_XB + 16777216;
  const size_t OFF_W2B_C = OFF_W1B_C + 16777216;
  const size_t OFF_H_C   = OFF_W2B_C + 16777216;
  const size_t OFF_YP_C  = OFF_H_C + (size_t)MAXPAIR * FCHUNK * 2;  // 86,319,360
  const size_t WS_CHUNK_YP = OFF_YP_C + (size_t)MAXPAIR * HID * 4;  // 157,622,528

  hipMemsetAsync(ws, 0, 139520, stream);

  gate_kernel<<<512, 256, 0, stream>>>(x, gw, gb, counts, probs, topk_e, topk_w);
  finalize_kernel<<<1, 64, 0, stream>>>(counts, cursors, offsets, probs,
                                        out + (out_size - 1));
  scatter_kernel<<<32, 256, 0, stream>>>(topk_e, topk_w, offsets, cursors, tok, wt, slot);
  stream_cvt_kernel<<<8192, 256, 0, stream>>>((const float4*)x, (u16x4*)xb);

  if (ws_size >= WS_FULL_AT) {
    // ---------------- full-FF path ----------------
    const bool yp = ws_size >= WS_FULL_YP;
    u16*   w1b   = (u16*)(ws + OFF_W1B_F);
    u16*   w2b   = (u16*)(ws + OFF_W2B_F);
    u16*   hbuf  = (u16*)(ws + OFF_H_F);
    float* ypair = (float*)(ws + OFF_YP_F);
    if (!yp) hipMemsetAsync(d_out, 0, (size_t)out_size * 4, stream);

    stream_cvt_kernel<<<32768, 256, 0, stream>>>((const float4*)w1, (u16x4*)w1b);
    stream_cvt_kernel<<<32768, 256, 0, stream>>>((const float4*)w2, (u16x4*)w2b);
    pass1_kernel<<<dim3(FF / BN, 136), 256, 0, stream>>>(xb, w1b, b1, tok, offsets,
                                                         hbuf, FF, 0);
    if (yp) {
      pass2_kernel<true><<<dim3(HID / BN, 136), 256, 0, stream>>>(
          hbuf, w2b, b2, tok, wt, offsets, ypair, out, FF, 0);
      combine_kernel<<<8192, 256, 0, stream>>>(ypair, slot, topk_e, topk_w, b2, out);
    } else {
      pass2_kernel<false><<<dim3(HID / BN, 136), 256, 0, stream>>>(
          hbuf, w2b, b2, tok, wt, offsets, ypair, out, FF, 0);
    }
  } else {
    // ---------------- chunked fallback (R1 path) ----------------
    const bool yp = ws_size >= WS_CHUNK_YP;
    u16*   w1b   = (u16*)(ws + OFF_W1B_C);
    u16*   w2b   = (u16*)(ws + OFF_W2B_C);
    u16*   hbuf  = (u16*)(ws + OFF_H_C);
    float* ypair = (float*)(ws + OFF_YP_C);
    if (!yp) hipMemsetAsync(d_out, 0, (size_t)out_size * 4, stream);

    for (int c = 0; c < NCHUNK; ++c) {
      cvt_w1_kernel<<<8192, 256, 0, stream>>>((const float4*)w1, (u16x4*)w1b, c);
      pass1_kernel<<<dim3(FCHUNK / BN, 136), 256, 0, stream>>>(xb, w1b, b1, tok, offsets,
                                                               hbuf, FCHUNK, c);
      cvt_w2_kernel<<<8192, 256, 0, stream>>>((const float4*)w2, (u16x4*)w2b, c);
      if (yp)
        pass2_kernel<true><<<dim3(HID / BN, 136), 256, 0, stream>>>(
            hbuf, w2b, b2, tok, wt, offsets, ypair, out, FCHUNK, c);
      else
        pass2_kernel<false><<<dim3(HID / BN, 136), 256, 0, stream>>>(
            hbuf, w2b, b2, tok, wt, offsets, ypair, out, FCHUNK, c);
    }
    if (yp)
      combine_kernel<<<8192, 256, 0, stream>>>(ypair, slot, topk_e, topk_w, b2, out);
  }
}

// Round 4
// 903.463 us; speedup vs baseline: 1.5265x; 1.0504x over previous
//
#include <hip/hip_runtime.h>
#include <cstdint>
#include <cstddef>

typedef unsigned short u16;
typedef short bf16x8 __attribute__((ext_vector_type(8)));
typedef float f32x4 __attribute__((ext_vector_type(4)));
typedef u16 u16x4 __attribute__((ext_vector_type(4)));

#define NTOK 8192
#define HID 1024
#define NEXP 8
#define FF 4096
#define FCHUNK 1024
#define NCHUNK 4
#define MAXPAIR 17408   // 2*NTOK + NEXP*128 padding headroom
#define BM 128
#define BN 128
#define BK 64

__device__ __forceinline__ u16 bf16_rne(float f) {
  unsigned u = __builtin_bit_cast(unsigned, f);
  return (u16)((u + 0x7FFFu + ((u >> 16) & 1u)) >> 16);
}

__device__ __forceinline__ float gelu_tanh(float v) {
  const float u = 0.7978845608028654f * (v + 0.044715f * v * v * v);
  const float e = __expf(2.0f * u);          // inf-safe: e=inf -> v; e=0 -> 0
  return v - v * __frcp_rn(e + 1.0f);
}

__device__ __forceinline__ void async16(const void* g, void* l) {
  __builtin_amdgcn_global_load_lds(
      (const __attribute__((address_space(1))) void*)g,
      (__attribute__((address_space(3))) void*)l, 16, 0, 0);
}

// ---------------- gate: logits, top-2, softmax probs ----------------
__global__ __launch_bounds__(256) void gate_kernel(
    const float* __restrict__ x, const float* __restrict__ gw,
    const float* __restrict__ gb, int* __restrict__ counts,
    float* __restrict__ probs_sum, int* __restrict__ topk_e,
    float* __restrict__ topk_w) {
  __shared__ float sgw[NEXP * HID];
  __shared__ float sProbs[NEXP];
  __shared__ int sCnt[NEXP];
  const int tid = threadIdx.x;
  for (int i = tid; i < NEXP * HID; i += 256) sgw[i] = gw[i];
  if (tid < NEXP) { sProbs[tid] = 0.f; sCnt[tid] = 0; }
  __syncthreads();
  const int lane = tid & 63, wave = tid >> 6;
  for (int it = 0; it < 4; ++it) {
    const int t = blockIdx.x * 16 + wave * 4 + it;
    const float* xr = x + (size_t)t * HID;
    float a[NEXP];
#pragma unroll
    for (int e = 0; e < NEXP; ++e) a[e] = 0.f;
    for (int j = 0; j < 16; ++j) {
      const int o = lane + 64 * j;
      const float v = xr[o];
#pragma unroll
      for (int e = 0; e < NEXP; ++e) a[e] += v * sgw[e * HID + o];
    }
#pragma unroll
    for (int off = 32; off > 0; off >>= 1)
#pragma unroll
      for (int e = 0; e < NEXP; ++e) a[e] += __shfl_xor(a[e], off);
    if (lane == 0) {
      float l[NEXP];
#pragma unroll
      for (int e = 0; e < NEXP; ++e) l[e] = a[e] + gb[e];
      int b0 = 0; float v0 = l[0];
#pragma unroll
      for (int e = 1; e < NEXP; ++e) if (l[e] > v0) { b0 = e; v0 = l[e]; }
      int b1i = (b0 == 0) ? 1 : 0; float v1 = l[b1i];
#pragma unroll
      for (int e = 0; e < NEXP; ++e) if (e != b0 && l[e] > v1) { b1i = e; v1 = l[e]; }
      const float e1 = __expf(v1 - v0);
      const float inv01 = 1.f / (1.f + e1);
      topk_e[2 * t] = b0; topk_e[2 * t + 1] = b1i;
      topk_w[2 * t] = inv01; topk_w[2 * t + 1] = e1 * inv01;
      atomicAdd(&sCnt[b0], 1); atomicAdd(&sCnt[b1i], 1);
      float s = 0.f, p[NEXP];
#pragma unroll
      for (int e = 0; e < NEXP; ++e) { p[e] = __expf(l[e] - v0); s += p[e]; }
      const float invs = 1.f / s;
#pragma unroll
      for (int e = 0; e < NEXP; ++e) atomicAdd(&sProbs[e], p[e] * invs);
    }
  }
  __syncthreads();
  if (tid < NEXP) {
    atomicAdd(&counts[tid], sCnt[tid]);
    atomicAdd(&probs_sum[tid], sProbs[tid]);
  }
}

// ---------------- finalize: padded prefix offsets + l_aux ----------------
__global__ void finalize_kernel(const int* __restrict__ counts,
                                int* __restrict__ cursors,
                                int* __restrict__ offsets,
                                const float* __restrict__ probs_sum,
                                float* __restrict__ laux) {
  if (threadIdx.x == 0) {
    int off = 0;
    for (int e = 0; e < NEXP; ++e) {
      offsets[e] = off;
      off += ((counts[e] + (BM - 1)) / BM) * BM;
      cursors[e] = 0;
    }
    offsets[NEXP] = off;
    float s = 0.f;
    for (int e = 0; e < NEXP; ++e) {
      const float p = probs_sum[e] * (1.f / (float)NTOK);
      s += p * p;
    }
    *laux = (float)NEXP * s;
  }
}

// ---------------- scatter tokens into per-expert pair lists ----------------
__global__ __launch_bounds__(256) void scatter_kernel(
    const int* __restrict__ topk_e, const float* __restrict__ topk_w,
    const int* __restrict__ offsets, int* __restrict__ cursors,
    int* __restrict__ tok_of_pair, float* __restrict__ wt_of_pair,
    int* __restrict__ slot_of_tok) {
  __shared__ int lcnt[NEXP], lbase[NEXP];
  const int tid = threadIdx.x;
  if (tid < NEXP) lcnt[tid] = 0;
  __syncthreads();
  const int t = blockIdx.x * 256 + tid;
  const int e0 = topk_e[2 * t], e1 = topk_e[2 * t + 1];
  const int p0 = atomicAdd(&lcnt[e0], 1);
  const int p1 = atomicAdd(&lcnt[e1], 1);
  __syncthreads();
  if (tid < NEXP) lbase[tid] = atomicAdd(&cursors[tid], lcnt[tid]);
  __syncthreads();
  const int s0 = offsets[e0] + lbase[e0] + p0;
  const int s1 = offsets[e1] + lbase[e1] + p1;
  tok_of_pair[s0] = t; wt_of_pair[s0] = topk_w[2 * t];
  tok_of_pair[s1] = t; wt_of_pair[s1] = topk_w[2 * t + 1];
  slot_of_tok[2 * t] = s0; slot_of_tok[2 * t + 1] = s1;
}

// ---------------- fp32 -> bf16 streaming convert ----------------
__global__ __launch_bounds__(256) void stream_cvt_kernel(const float4* __restrict__ src,
                                                         u16x4* __restrict__ dst) {
  const int i = blockIdx.x * 256 + threadIdx.x;
  const float4 v = src[i];
  u16x4 o;
  o[0] = bf16_rne(v.x); o[1] = bf16_rne(v.y); o[2] = bf16_rne(v.z); o[3] = bf16_rne(v.w);
  dst[i] = o;
}

// chunked converts (fallback path)
__global__ __launch_bounds__(256) void cvt_w1_kernel(const float4* __restrict__ w1,
                                                     u16x4* __restrict__ w1b, int c) {
  const int i = blockIdx.x * 256 + threadIdx.x;  // 2097152 total
  const int e = i >> 18;
  const int r = i & 262143;
  const float4 v = w1[(size_t)e * 1048576 + (size_t)c * 262144 + r];
  u16x4 o;
  o[0] = bf16_rne(v.x); o[1] = bf16_rne(v.y); o[2] = bf16_rne(v.z); o[3] = bf16_rne(v.w);
  w1b[i] = o;
}

__global__ __launch_bounds__(256) void cvt_w2_kernel(const float4* __restrict__ w2,
                                                     u16x4* __restrict__ w2b, int c) {
  const int i = blockIdx.x * 256 + threadIdx.x;  // 2097152 total
  const int e = i >> 18;
  const int r = i & 262143;
  const int o = r >> 8;
  const int j4 = r & 255;
  const float4 v = w2[(size_t)e * 1048576 + (size_t)o * 1024 + (size_t)c * 256 + j4];
  u16x4 ov;
  ov[0] = bf16_rne(v.x); ov[1] = bf16_rne(v.y); ov[2] = bf16_rne(v.z); ov[3] = bf16_rne(v.w);
  w2b[i] = ov;
}

// ============ GEMM kernels with XOR-swizzled LDS (kills bank conflicts) ======
// Physical LDS slot (row, g) holds logical 16B-group g ^ (row&7). Staging
// permutes the GLOBAL source column (same 128B line -> coalescing intact);
// global_load_lds dest stays lane-contiguous as HW requires (m104/m108).

// ---------------- pass1: h = gelu(x @ w1^T + b1), N = ffN ----------------
__global__ __launch_bounds__(256) void pass1_kernel(
    const u16* __restrict__ xb, const u16* __restrict__ w1b,
    const float* __restrict__ b1, const int* __restrict__ tok_of_pair,
    const int* __restrict__ offsets, u16* __restrict__ h, const int ffN,
    const int chunk) {
  __shared__ u16 As[BM * BK];
  __shared__ u16 Bs[BN * BK];
  const int nt = blockIdx.x, mt = blockIdx.y;
  const int base = mt * BM;
  if (base >= offsets[NEXP]) return;
  int e = 0;
  while (e < NEXP - 1 && base >= offsets[e + 1]) ++e;
  const int tid = threadIdx.x;
  const int lane = tid & 63;
  const int wave = tid >> 6;
  const int wm = wave & 1, wn = wave >> 1;
  const int srow = tid >> 3;
  const int scol = (tid & 7) * 8;                       // physical LDS group
  const int scolg = (((tid & 7) ^ ((tid >> 3) & 7)) * 8);  // swizzled global group
  int tokA[4];
#pragma unroll
  for (int i = 0; i < 4; ++i) tokA[i] = tok_of_pair[base + i * 32 + srow];
  const u16* wB = w1b + (size_t)e * ((size_t)ffN * HID) + (size_t)(nt * BN) * HID;
  f32x4 acc[4][4];
#pragma unroll
  for (int i = 0; i < 4; ++i)
#pragma unroll
    for (int j = 0; j < 4; ++j) acc[i][j] = (f32x4){0.f, 0.f, 0.f, 0.f};

  for (int k0 = 0; k0 < HID; k0 += BK) {
#pragma unroll
    for (int i = 0; i < 4; ++i) {
      async16(xb + (size_t)tokA[i] * HID + k0 + scolg, &As[(i * 32 + srow) * BK + scol]);
      async16(wB + (size_t)(i * 32 + srow) * HID + k0 + scolg, &Bs[(i * 32 + srow) * BK + scol]);
    }
    __syncthreads();
    const int nl = lane & 15;
    const int q = lane >> 4;
    const int sw = nl & 7;
#pragma unroll
    for (int s = 0; s < 2; ++s) {
      const int kg = ((s * 4 + q) ^ sw) * 8;   // swizzled physical col
      bf16x8 af[4], bf[4];
#pragma unroll
      for (int i = 0; i < 4; ++i)
        af[i] = *(const bf16x8*)&As[(wm * 64 + i * 16 + nl) * BK + kg];
#pragma unroll
      for (int j = 0; j < 4; ++j)
        bf[j] = *(const bf16x8*)&Bs[(wn * 64 + j * 16 + nl) * BK + kg];
#pragma unroll
      for (int i = 0; i < 4; ++i)
#pragma unroll
        for (int j = 0; j < 4; ++j)
          acc[i][j] = __builtin_amdgcn_mfma_f32_16x16x32_bf16(af[i], bf[j], acc[i][j], 0, 0, 0);
    }
    __syncthreads();
  }
  const int nl = lane & 15;
  const int rowq = (lane >> 4) * 4;
  const float* b1e = b1 + (size_t)e * FF + (size_t)chunk * FCHUNK;
#pragma unroll
  for (int i = 0; i < 4; ++i) {
#pragma unroll
    for (int j = 0; j < 4; ++j) {
      const int n = nt * BN + wn * 64 + j * 16 + nl;
      const float bias = b1e[n];
#pragma unroll
      for (int r = 0; r < 4; ++r) {
        const int m = base + wm * 64 + i * 16 + rowq + r;
        h[(size_t)m * ffN + n] = bf16_rne(gelu_tanh(acc[i][j][r] + bias));
      }
    }
  }
}

// ---------------- pass2: ypair[m] += h @ w2^T (YP) or atomic out, K = kTot ----
template <bool YP>
__global__ __launch_bounds__(256) void pass2_kernel(
    const u16* __restrict__ h, const u16* __restrict__ w2b,
    const float* __restrict__ b2, const int* __restrict__ tok_of_pair,
    const float* __restrict__ wt_of_pair, const int* __restrict__ offsets,
    float* __restrict__ ypair, float* __restrict__ out, const int kTot,
    const int chunk) {
  __shared__ u16 As[BM * BK];
  __shared__ u16 Bs[BN * BK];
  const int nt = blockIdx.x, mt = blockIdx.y;
  const int base = mt * BM;
  if (base >= offsets[NEXP]) return;
  int e = 0;
  while (e < NEXP - 1 && base >= offsets[e + 1]) ++e;
  const int tid = threadIdx.x;
  const int lane = tid & 63;
  const int wave = tid >> 6;
  const int wm = wave & 1, wn = wave >> 1;
  const int srow = tid >> 3;
  const int scol = (tid & 7) * 8;
  const int scolg = (((tid & 7) ^ ((tid >> 3) & 7)) * 8);
  const u16* wB = w2b + (size_t)e * ((size_t)HID * kTot) + (size_t)(nt * BN) * kTot;
  f32x4 acc[4][4];
#pragma unroll
  for (int i = 0; i < 4; ++i)
#pragma unroll
    for (int j = 0; j < 4; ++j) acc[i][j] = (f32x4){0.f, 0.f, 0.f, 0.f};

  for (int k0 = 0; k0 < kTot; k0 += BK) {
#pragma unroll
    for (int i = 0; i < 4; ++i) {
      async16(h + (size_t)(base + i * 32 + srow) * kTot + k0 + scolg,
              &As[(i * 32 + srow) * BK + scol]);
      async16(wB + (size_t)(i * 32 + srow) * kTot + k0 + scolg,
              &Bs[(i * 32 + srow) * BK + scol]);
    }
    __syncthreads();
    const int nl = lane & 15;
    const int q = lane >> 4;
    const int sw = nl & 7;
#pragma unroll
    for (int s = 0; s < 2; ++s) {
      const int kg = ((s * 4 + q) ^ sw) * 8;
      bf16x8 af[4], bf[4];
#pragma unroll
      for (int i = 0; i < 4; ++i)
        af[i] = *(const bf16x8*)&As[(wm * 64 + i * 16 + nl) * BK + kg];
#pragma unroll
      for (int j = 0; j < 4; ++j)
        bf[j] = *(const bf16x8*)&Bs[(wn * 64 + j * 16 + nl) * BK + kg];
#pragma unroll
      for (int i = 0; i < 4; ++i)
#pragma unroll
        for (int j = 0; j < 4; ++j)
          acc[i][j] = __builtin_amdgcn_mfma_f32_16x16x32_bf16(af[i], bf[j], acc[i][j], 0, 0, 0);
    }
    __syncthreads();
  }
  const int nl = lane & 15;
  const int rowq = (lane >> 4) * 4;
  if (YP) {
#pragma unroll
    for (int i = 0; i < 4; ++i) {
#pragma unroll
      for (int r = 0; r < 4; ++r) {
        const int m = base + wm * 64 + i * 16 + rowq + r;
        float* yrow = ypair + (size_t)m * HID;
#pragma unroll
        for (int j = 0; j < 4; ++j) {
          const int o = nt * BN + wn * 64 + j * 16 + nl;
          float v = acc[i][j][r];
          if (chunk != 0) v += yrow[o];
          yrow[o] = v;
        }
      }
    }
  } else {
    const float* b2e = b2 + (size_t)e * HID;
#pragma unroll
    for (int i = 0; i < 4; ++i) {
#pragma unroll
      for (int r = 0; r < 4; ++r) {
        const int m = base + wm * 64 + i * 16 + rowq + r;
        const int tokm = tok_of_pair[m];
        const float wtm = wt_of_pair[m];
        float* orow = out + (size_t)tokm * HID;
#pragma unroll
        for (int j = 0; j < 4; ++j) {
          const int o = nt * BN + wn * 64 + j * 16 + nl;
          float v = acc[i][j][r];
          if (chunk == 0) v += b2e[o];
          atomicAdd(&orow[o], wtm * v);
        }
      }
    }
  }
}

// ---------------- combine: out[t] = w0*(y[s0]+b2[e0]) + w1*(y[s1]+b2[e1]) ----
__global__ __launch_bounds__(256) void combine_kernel(
    const float* __restrict__ ypair, const int* __restrict__ slot_of_tok,
    const int* __restrict__ topk_e, const float* __restrict__ topk_w,
    const float* __restrict__ b2, float* __restrict__ out) {
  const int t = blockIdx.x;
  const int tid = threadIdx.x;
  const int s0 = slot_of_tok[2 * t], s1 = slot_of_tok[2 * t + 1];
  const int e0 = topk_e[2 * t], e1 = topk_e[2 * t + 1];
  const float w0 = topk_w[2 * t], w1v = topk_w[2 * t + 1];
  const float4 y0 = ((const float4*)(ypair + (size_t)s0 * HID))[tid];
  const float4 y1 = ((const float4*)(ypair + (size_t)s1 * HID))[tid];
  const float4 c0 = ((const float4*)(b2 + (size_t)e0 * HID))[tid];
  const float4 c1 = ((const float4*)(b2 + (size_t)e1 * HID))[tid];
  float4 o;
  o.x = w0 * (y0.x + c0.x) + w1v * (y1.x + c1.x);
  o.y = w0 * (y0.y + c0.y) + w1v * (y1.y + c1.y);
  o.z = w0 * (y0.z + c0.z) + w1v * (y1.z + c1.z);
  o.w = w0 * (y0.w + c0.w) + w1v * (y1.w + c1.w);
  ((float4*)(out + (size_t)t * HID))[tid] = o;
}

extern "C" void kernel_launch(void* const* d_in, const int* in_sizes, int n_in,
                              void* d_out, int out_size, void* d_ws, size_t ws_size,
                              hipStream_t stream) {
  (void)in_sizes; (void)n_in;
  const float* x  = (const float*)d_in[0];
  const float* gw = (const float*)d_in[1];
  const float* gb = (const float*)d_in[2];
  const float* w1 = (const float*)d_in[3];
  const float* b1 = (const float*)d_in[4];
  const float* w2 = (const float*)d_in[5];
  const float* b2 = (const float*)d_in[6];
  float* out = (float*)d_out;

  char* ws = (char*)d_ws;
  // control region (shared by all paths)
  int*   counts  = (int*)(ws + 0);
  int*   cursors = (int*)(ws + 32);
  float* probs   = (float*)(ws + 64);
  int*   offsets = (int*)(ws + 96);
  int*   tok     = (int*)(ws + 256);                       // MAXPAIR ints
  float* wt      = (float*)(ws + 256 + 4 * MAXPAIR);       // -> ends 139520
  int*   topk_e  = (int*)(ws + 139520);                    // -> 205056
  float* topk_w  = (float*)(ws + 205056);                  // -> 270592
  int*   slot    = (int*)(ws + 270592);                    // -> 336128
  const size_t OFF_XB = 336128;
  u16* xb = (u16*)(ws + OFF_XB);                           // 16,777,216 B

  // ---- full-FF layout ----
  const size_t OFF_W1B_F = OFF_XB + 16777216;              // 17,113,344
  const size_t OFF_W2B_F = OFF_W1B_F + 67108864;           // 84,222,208
  const size_t OFF_H_F   = OFF_W2B_F + 67108864;           // 151,331,072
  const size_t OFF_YP_F  = OFF_H_F + (size_t)MAXPAIR * FF * 2;    // 293,937,408
  const size_t WS_FULL_AT = OFF_YP_F;                             // full, atomic epilogue
  const size_t WS_FULL_YP = OFF_YP_F + (size_t)MAXPAIR * HID * 4; // 365,240,576

  // ---- chunked layout (proven R1) ----
  const size_t OFF_W1B_C = OFF_XB + 16777216;
  const size_t OFF_W2B_C = OFF_W1B_C + 16777216;
  const size_t OFF_H_C   = OFF_W2B_C + 16777216;
  const size_t OFF_YP_C  = OFF_H_C + (size_t)MAXPAIR * FCHUNK * 2;  // 86,319,360
  const size_t WS_CHUNK_YP = OFF_YP_C + (size_t)MAXPAIR * HID * 4;  // 157,622,528

  hipMemsetAsync(ws, 0, 139520, stream);

  gate_kernel<<<512, 256, 0, stream>>>(x, gw, gb, counts, probs, topk_e, topk_w);
  finalize_kernel<<<1, 64, 0, stream>>>(counts, cursors, offsets, probs,
                                        out + (out_size - 1));
  scatter_kernel<<<32, 256, 0, stream>>>(topk_e, topk_w, offsets, cursors, tok, wt, slot);
  stream_cvt_kernel<<<8192, 256, 0, stream>>>((const float4*)x, (u16x4*)xb);

  if (ws_size >= WS_FULL_AT) {
    // ---------------- full-FF path ----------------
    const bool yp = ws_size >= WS_FULL_YP;
    u16*   w1b   = (u16*)(ws + OFF_W1B_F);
    u16*   w2b   = (u16*)(ws + OFF_W2B_F);
    u16*   hbuf  = (u16*)(ws + OFF_H_F);
    float* ypair = (float*)(ws + OFF_YP_F);
    if (!yp) hipMemsetAsync(d_out, 0, (size_t)out_size * 4, stream);

    stream_cvt_kernel<<<32768, 256, 0, stream>>>((const float4*)w1, (u16x4*)w1b);
    stream_cvt_kernel<<<32768, 256, 0, stream>>>((const float4*)w2, (u16x4*)w2b);
    pass1_kernel<<<dim3(FF / BN, 136), 256, 0, stream>>>(xb, w1b, b1, tok, offsets,
                                                         hbuf, FF, 0);
    if (yp) {
      pass2_kernel<true><<<dim3(HID / BN, 136), 256, 0, stream>>>(
          hbuf, w2b, b2, tok, wt, offsets, ypair, out, FF, 0);
      combine_kernel<<<8192, 256, 0, stream>>>(ypair, slot, topk_e, topk_w, b2, out);
    } else {
      pass2_kernel<false><<<dim3(HID / BN, 136), 256, 0, stream>>>(
          hbuf, w2b, b2, tok, wt, offsets, ypair, out, FF, 0);
    }
  } else {
    // ---------------- chunked fallback (R1 path) ----------------
    const bool yp = ws_size >= WS_CHUNK_YP;
    u16*   w1b   = (u16*)(ws + OFF_W1B_C);
    u16*   w2b   = (u16*)(ws + OFF_W2B_C);
    u16*   hbuf  = (u16*)(ws + OFF_H_C);
    float* ypair = (float*)(ws + OFF_YP_C);
    if (!yp) hipMemsetAsync(d_out, 0, (size_t)out_size * 4, stream);

    for (int c = 0; c < NCHUNK; ++c) {
      cvt_w1_kernel<<<8192, 256, 0, stream>>>((const float4*)w1, (u16x4*)w1b, c);
      pass1_kernel<<<dim3(FCHUNK / BN, 136), 256, 0, stream>>>(xb, w1b, b1, tok, offsets,
                                                               hbuf, FCHUNK, c);
      cvt_w2_kernel<<<8192, 256, 0, stream>>>((const float4*)w2, (u16x4*)w2b, c);
      if (yp)
        pass2_kernel<true><<<dim3(HID / BN, 136), 256, 0, stream>>>(
            hbuf, w2b, b2, tok, wt, offsets, ypair, out, FCHUNK, c);
      else
        pass2_kernel<false><<<dim3(HID / BN, 136), 256, 0, stream>>>(
            hbuf, w2b, b2, tok, wt, offsets, ypair, out, FCHUNK, c);
    }
    if (yp)
      combine_kernel<<<8192, 256, 0, stream>>>(ypair, slot, topk_e, topk_w, b2, out);
  }
}